// Round 8
// baseline (252.979 us; speedup 1.0000x reference)
//
#include <hip/hip_runtime.h>
#include <hip/hip_bf16.h>
#include <stdint.h>

typedef __attribute__((ext_vector_type(4))) float f32x4;
typedef __attribute__((ext_vector_type(8))) short s16x8;
typedef __attribute__((ext_vector_type(4))) short s16x4;

// XOR-swizzle of 16B-granule index within a 128B row (involution on low 3 bits)
#define SWZ(g, row) ((((g) & ~7) | (((g) ^ ((row) & 7)) & 7)))

__device__ __forceinline__ unsigned short f2bf(float f) {
  unsigned u = __builtin_bit_cast(unsigned, f);
  u += 0x7fffu + ((u >> 16) & 1u);   // round-to-nearest-even
  return (unsigned short)(u >> 16);
}

__device__ __forceinline__ void gld16(const void* g, void* l) {
  __builtin_amdgcn_global_load_lds(
      (const __attribute__((address_space(1))) void*)g,
      (__attribute__((address_space(3))) void*)l, 16, 0, 0);
}

// ---------------------------------------------------------------- fused convert
// one kernel for x (2097152 f4), qkvw (3145728 f4), ow (1048576 f4);
// segment boundaries are multiples of 256 -> block-uniform branches.
__global__ void cvt_all(const float* __restrict__ x, const float* __restrict__ qkvw,
                        const float* __restrict__ ow, unsigned short* __restrict__ X16,
                        unsigned short* __restrict__ W16, unsigned short* __restrict__ OW16) {
  int i = blockIdx.x * blockDim.x + threadIdx.x;
  const float* src; unsigned short* dst; int off;
  if (i < 2097152)      { src = x;    dst = X16;  off = i; }
  else if (i < 5242880) { src = qkvw; dst = W16;  off = i - 2097152; }
  else                  { src = ow;   dst = OW16; off = i - 5242880; }
  float4 v = ((const float4*)src)[off];
  s16x4 o;
  o[0] = (short)f2bf(v.x); o[1] = (short)f2bf(v.y);
  o[2] = (short)f2bf(v.z); o[3] = (short)f2bf(v.w);
  ((s16x4*)dst)[off] = o;
}

// ---------------------------------------------------------------- QKV GEMM, 128x384 tile
// r8: m201-style fine phases. Per K-tile, 4 snake phases (ks0C0, ks0C1, ks1C1,
// ks1C0); each phase loads exactly one new operand half and does 12 MFMA between
// raw barriers. Stage-at-top + counted vmcnt(8) ledger (1-tile lookahead).
#define STAGE384(BB, KT) \
  { char* dA = smem + (BB) * 65536; \
    char* dB = dA + 16384; \
    _Pragma("unroll") for (int rr = 0; rr < 2; ++rr) { \
      const int G = rr * 512 + tid; const int row = G >> 3, g = G & 7; \
      gld16((const char*)(Aorg + (size_t)row * 2048 + (size_t)(KT) * 64) + (SWZ(g, row) << 4), \
            dA + rr * 8192 + tid * 16); } \
    _Pragma("unroll") for (int rr = 0; rr < 6; ++rr) { \
      const int G = rr * 512 + tid; const int row = G >> 3, g = G & 7; \
      gld16((const char*)(Borg + (size_t)row * 2048 + (size_t)(KT) * 64) + (SWZ(g, row) << 4), \
            dB + rr * 8192 + tid * 16); } }

#define RDA(KS) \
  _Pragma("unroll") for (int j = 0; j < 4; ++j) { \
    const int ra = wm * 64 + j * 16 + lg; \
    av[j] = *(const s16x8*)(sA + ra * 128 + (SWZ(4 * (KS) + hg, ra) << 4)); }

#define RDB(KS, CH) \
  _Pragma("unroll") for (int b = 0; b < 3; ++b) { \
    const int bb = (CH) * 3 + b; \
    const int cb = (bb >> 1) * 128 + wn * 16 + (bb & 1) * 64 + lg; \
    bv[b] = *(const s16x8*)(sB + cb * 128 + (SWZ(4 * (KS) + hg, cb) << 4)); }

#define MM12(CH) \
  _Pragma("unroll") for (int j = 0; j < 4; ++j) \
    _Pragma("unroll") for (int b = 0; b < 3; ++b) \
      acc[j][(CH) * 3 + b] = __builtin_amdgcn_mfma_f32_16x16x32_bf16( \
          av[j], bv[b], acc[j][(CH) * 3 + b], 0, 0, 0);

#define PH_PRE \
  __builtin_amdgcn_s_barrier(); \
  asm volatile("s_waitcnt lgkmcnt(0)" ::: "memory"); \
  __builtin_amdgcn_sched_barrier(0); \
  __builtin_amdgcn_s_setprio(1);

#define PH_POST \
  __builtin_amdgcn_s_setprio(0); \
  __builtin_amdgcn_s_barrier();

__global__ __launch_bounds__(512, 1) void gemm_qkv_384(
    const unsigned short* __restrict__ A,
    const unsigned short* __restrict__ Bt,
    const float* __restrict__ cosT, const float* __restrict__ sinT,
    unsigned short* __restrict__ qOut, unsigned short* __restrict__ kOut,
    unsigned short* __restrict__ vtOut)
{
  __shared__ char smem[131072];   // buf b: A @ b*65536 (16KB), B @ +16384 (48KB)
  const int tid = (int)threadIdx.x;
  const int wid = tid >> 6, l = tid & 63;
  const int lg = l & 15, hg = l >> 4;
  const int wm = wid >> 2, wn = wid & 3;
  const int s = ((int)blockIdx.x & 7) * 64 + ((int)blockIdx.x >> 3);
  const int bm0 = (s & 31) * 128, bn0 = (s >> 5) * 384;

  const unsigned short* Aorg = A + (size_t)bm0 * 2048;
  const unsigned short* Borg = Bt + (size_t)bn0 * 2048;

  f32x4 acc[4][6] = {};

  STAGE384(0, 0)
  for (int t = 0; t < 31; ++t) {
    STAGE384((t & 1) ^ 1, t + 1)
    asm volatile("s_waitcnt vmcnt(8)" ::: "memory");   // tile t landed (this wave)
    __builtin_amdgcn_s_barrier();                       // ... and all waves
    const char* sA = smem + (t & 1) * 65536;
    const char* sB = sA + 16384;
    s16x8 av[4], bv[3];
    RDA(0) RDB(0, 0)  PH_PRE  MM12(0)  PH_POST
    RDB(0, 1)         PH_PRE  MM12(1)  PH_POST
    RDA(1) RDB(1, 1)  PH_PRE  MM12(1)  PH_POST
    RDB(1, 0)         PH_PRE  MM12(0)  PH_POST        // final barrier: buf[t] free
  }
  {  // last tile t = 31 (buf 1), drain
    asm volatile("s_waitcnt vmcnt(0)" ::: "memory");
    __builtin_amdgcn_s_barrier();
    const char* sA = smem + 65536;
    const char* sB = sA + 16384;
    s16x8 av[4], bv[3];
    RDA(0) RDB(0, 0)  PH_PRE  MM12(0)  PH_POST
    RDB(0, 1)         PH_PRE  MM12(1)  PH_POST
    RDA(1) RDB(1, 1)  PH_PRE  MM12(1)  PH_POST
    RDB(1, 0)         PH_PRE  MM12(0)  PH_POST
  }

  // ---- epilogue: rotary for q/k head-groups, transposed-V for v head-groups
  #pragma unroll
  for (int j = 0; j < 4; ++j) {
    const int grow0 = bm0 + wm * 64 + j * 16 + hg * 4;
    const int b_ = grow0 >> 11;
    #pragma unroll
    for (int cg = 0; cg < 3; ++cg) {
      const int og = (bn0 >> 7) + cg;
      const int tt = og >> 4, h = og & 15;
      const int d = wn * 16 + lg;
      if (tt < 2) {
        unsigned short* dst = (tt == 0) ? qOut : kOut;
        #pragma unroll
        for (int r = 0; r < 4; ++r) {
          const int gr = grow0 + r;
          const int s1 = gr & 2047;
          const float x1 = acc[j][cg * 2 + 0][r];
          const float x2 = acc[j][cg * 2 + 1][r];
          const float cv = cosT[s1 * 64 + d];
          const float sv = sinT[s1 * 64 + d];
          const size_t base = (((size_t)b_ * 16 + h) * 2048 + s1) * 128;
          dst[base + d]      = f2bf(x1 * cv - x2 * sv);
          dst[base + d + 64] = f2bf(x2 * cv + x1 * sv);
        }
      } else {
        const int s0 = grow0 & 2047;
        s16x4 p1, p2;
        #pragma unroll
        for (int r = 0; r < 4; ++r) {
          p1[r] = (short)f2bf(acc[j][cg * 2 + 0][r]);
          p2[r] = (short)f2bf(acc[j][cg * 2 + 1][r]);
        }
        *(s16x4*)(vtOut + (((size_t)b_ * 16 + h) * 128 + d)      * 2048 + s0) = p1;
        *(s16x4*)(vtOut + (((size_t)b_ * 16 + h) * 128 + d + 64) * 2048 + s0) = p2;
      }
    }
  }
}

// ---------------------------------------------------------------- out-proj GEMM, 128x256
// Same fine-phase structure; 256 blocks = exactly 1 dispatch round; vmcnt(6).
#define STAGEOP(BB, KT) \
  { char* dA = smem + (BB) * 49152; \
    char* dB = dA + 16384; \
    _Pragma("unroll") for (int rr = 0; rr < 2; ++rr) { \
      const int G = rr * 512 + tid; const int row = G >> 3, g = G & 7; \
      gld16((const char*)(Aorg + (size_t)row * 2048 + (size_t)(KT) * 64) + (SWZ(g, row) << 4), \
            dA + rr * 8192 + tid * 16); } \
    _Pragma("unroll") for (int rr = 0; rr < 4; ++rr) { \
      const int G = rr * 512 + tid; const int row = G >> 3, g = G & 7; \
      gld16((const char*)(Borg + (size_t)row * 2048 + (size_t)(KT) * 64) + (SWZ(g, row) << 4), \
            dB + rr * 8192 + tid * 16); } }

#define RDBO(KS, CH) \
  _Pragma("unroll") for (int b = 0; b < 2; ++b) { \
    const int cb = ((CH) * 2 + b) * 64 + wn * 16 + lg; \
    bv[b] = *(const s16x8*)(sB + cb * 128 + (SWZ(4 * (KS) + hg, cb) << 4)); }

#define MMO(CH) \
  _Pragma("unroll") for (int j = 0; j < 4; ++j) \
    _Pragma("unroll") for (int b = 0; b < 2; ++b) \
      acc[j][(CH) * 2 + b] = __builtin_amdgcn_mfma_f32_16x16x32_bf16( \
          av[j], bv[b], acc[j][(CH) * 2 + b], 0, 0, 0);

__global__ __launch_bounds__(512, 1) void gemm_op_256(
    const unsigned short* __restrict__ A,
    const unsigned short* __restrict__ Bt,
    float* __restrict__ C)
{
  __shared__ char smem[98304];   // buf b @ b*49152: A 16KB, B 32KB
  const int tid = (int)threadIdx.x;
  const int wid = tid >> 6, l = tid & 63;
  const int lg = l & 15, hg = l >> 4;
  const int wm = wid >> 2, wn = wid & 3;
  const int s = ((int)blockIdx.x & 7) * 32 + ((int)blockIdx.x >> 3);
  const int bm0 = (s & 31) * 128, bn0 = (s >> 5) * 256;

  const unsigned short* Aorg = A + (size_t)bm0 * 2048;
  const unsigned short* Borg = Bt + (size_t)bn0 * 2048;

  f32x4 acc[4][4] = {};

  STAGEOP(0, 0)
  for (int t = 0; t < 31; ++t) {
    STAGEOP((t & 1) ^ 1, t + 1)
    asm volatile("s_waitcnt vmcnt(6)" ::: "memory");
    __builtin_amdgcn_s_barrier();
    const char* sA = smem + (t & 1) * 49152;
    const char* sB = sA + 16384;
    s16x8 av[4], bv[2];
    RDA(0) RDBO(0, 0)  PH_PRE  MMO(0)  PH_POST
    RDBO(0, 1)         PH_PRE  MMO(1)  PH_POST
    RDA(1) RDBO(1, 1)  PH_PRE  MMO(1)  PH_POST
    RDBO(1, 0)         PH_PRE  MMO(0)  PH_POST
  }
  {
    asm volatile("s_waitcnt vmcnt(0)" ::: "memory");
    __builtin_amdgcn_s_barrier();
    const char* sA = smem + 49152;
    const char* sB = sA + 16384;
    s16x8 av[4], bv[2];
    RDA(0) RDBO(0, 0)  PH_PRE  MMO(0)  PH_POST
    RDBO(0, 1)         PH_PRE  MMO(1)  PH_POST
    RDA(1) RDBO(1, 1)  PH_PRE  MMO(1)  PH_POST
    RDBO(1, 0)         PH_PRE  MMO(0)  PH_POST
  }

  #pragma unroll
  for (int j = 0; j < 4; ++j) {
    const int row0 = bm0 + wm * 64 + j * 16 + hg * 4;
    #pragma unroll
    for (int b = 0; b < 4; ++b) {
      const int col = bn0 + b * 64 + wn * 16 + lg;
      #pragma unroll
      for (int r = 0; r < 4; ++r)
        C[(size_t)(row0 + r) * 2048 + col] = acc[j][b][r];
    }
  }
}

// ---------------------------------------------------------------- flash attention
// grid: 1024 blocks. Balanced mapping: dispatch places bids {b,b+256,b+512,b+768}
// on one CU (4 resident at 40KB LDS); give those qt = {j,31-j,8+j,23-j} so every
// CU owns exactly 66 KV-tile-units. bh = c&31 keeps 4 heads per XCD (L2-resident).
__global__ __launch_bounds__(256) void attn_fwd(
    const unsigned short* __restrict__ Qp, const unsigned short* __restrict__ Kp,
    const unsigned short* __restrict__ Vt, unsigned short* __restrict__ AO)
{
  __shared__ char sK[16384];   // [64][128] bf16, 16 granules/row, swizzled
  __shared__ char sV[16384];   // [128][64] bf16 (Vt tile), 8 granules/row, swizzled
  __shared__ char sP[8192];    // per-wave [16][64] bf16, swizzled

  const int tid = (int)threadIdx.x, w = tid >> 6, l = tid & 63;
  const int lg = l & 15, hg = l >> 4;
  const int bid = (int)blockIdx.x;
  const int p = bid >> 8, c = bid & 255;
  const int j = c >> 5, bh = c & 31;
  const int qt = (p == 0) ? j : (p == 1) ? 31 - j : (p == 2) ? 8 + j : 23 - j;
  const size_t qkBase = (size_t)bh * 2048 * 128;
  const int qw0 = qt * 64 + w * 16;
  const int qi = qw0 + lg;

  s16x8 qf[4];
  for (int ks = 0; ks < 4; ++ks)
    qf[ks] = *(const s16x8*)(Qp + qkBase + (size_t)(qw0 + lg) * 128 + ks * 32 + hg * 8);

  f32x4 acc_o[8] = {};
  float mrun = -1e30f, lrun = 0.f;
  const float SCALE = 0.08838834764831845f;   // 1/sqrt(128)
  const float L2E = 1.4426950408889634f;
  const float CS = SCALE * L2E;

  const int nkv = qt + 1;
  for (int kv = 0; kv < nkv; ++kv) {
    const int kv0 = kv * 64;
    __syncthreads();
    for (int i = 0; i < 4; ++i) {
      const int G = w * 256 + i * 64 + l;
      const int rk = G >> 4, gk = G & 15;
      gld16((const char*)(Kp + qkBase + (size_t)(kv0 + rk) * 128) + (SWZ(gk, rk) << 4),
            sK + w * 4096 + i * 1024);
      const int rv = G >> 3, gv = G & 7;
      gld16((const char*)(Vt + qkBase + (size_t)rv * 2048 + kv0) + (SWZ(gv, rv) << 4),
            sV + w * 4096 + i * 1024);
    }
    asm volatile("s_waitcnt vmcnt(0)" ::: "memory");
    __syncthreads();

    f32x4 accs[4] = {};
    for (int ks = 0; ks < 4; ++ks)
      for (int kf = 0; kf < 4; ++kf) {
        const int row = kf * 16 + lg;
        const int g = SWZ(4 * ks + hg, row);
        s16x8 kfrag = *(const s16x8*)(sK + row * 256 + (g << 4));
        accs[kf] = __builtin_amdgcn_mfma_f32_16x16x32_bf16(kfrag, qf[ks], accs[kf], 0, 0, 0);
      }

    const bool diag = (kv == qt);
    float raw[4][4];
    float mt = -1e30f;
    #pragma unroll
    for (int kf = 0; kf < 4; ++kf)
      #pragma unroll
      for (int r = 0; r < 4; ++r) {
        float s = accs[kf][r];
        if (diag) {
          const int jj = kv0 + kf * 16 + hg * 4 + r;
          s = (jj > qi) ? -1e30f : s;
        }
        raw[kf][r] = s;
        mt = fmaxf(mt, s);
      }
    mt = fmaxf(mt, __shfl_xor(mt, 16));
    mt = fmaxf(mt, __shfl_xor(mt, 32));
    mt *= SCALE;
    if (!__all(mt - mrun <= 8.0f)) {
      const float mnew = fmaxf(mrun, mt);
      const float alpha = exp2f((mrun - mnew) * L2E);
      float ar[4];
      #pragma unroll
      for (int r = 0; r < 4; ++r) ar[r] = __shfl(alpha, hg * 4 + r);
      #pragma unroll
      for (int f = 0; f < 8; ++f)
        #pragma unroll
        for (int r = 0; r < 4; ++r) acc_o[f][r] *= ar[r];
      lrun *= alpha;
      mrun = mnew;
    }
    const float mL = mrun * L2E;
    float ls = 0.f;
    char* pw = sP + w * 2048;
    #pragma unroll
    for (int kf = 0; kf < 4; ++kf) {
      s16x4 pk;
      #pragma unroll
      for (int r = 0; r < 4; ++r) {
        const float e = exp2f(raw[kf][r] * CS - mL);
        ls += e;
        pk[r] = (short)f2bf(e);
      }
      const int j0 = kf * 16 + hg * 4;
      *(s16x4*)(pw + lg * 128 + (SWZ(j0 >> 3, lg) << 4) + ((j0 * 2) & 15)) = pk;
    }
    ls += __shfl_xor(ls, 16);
    ls += __shfl_xor(ls, 32);
    lrun += ls;
    asm volatile("" ::: "memory");

    for (int jc = 0; jc < 2; ++jc) {
      const int gp = SWZ(hg + 4 * jc, lg);
      s16x8 pa = *(const s16x8*)(pw + lg * 128 + (gp << 4));
      for (int f = 0; f < 8; ++f) {
        const int rv = f * 16 + lg;
        const int gv = SWZ(hg + 4 * jc, rv);
        s16x8 vb = *(const s16x8*)(sV + rv * 128 + (gv << 4));
        acc_o[f] = __builtin_amdgcn_mfma_f32_16x16x32_bf16(pa, vb, acc_o[f], 0, 0, 0);
      }
    }
  }

  float linv[4];
  for (int r = 0; r < 4; ++r) linv[r] = 1.0f / __shfl(lrun, hg * 4 + r);
  const int b = bh >> 4, h = bh & 15;
  for (int f = 0; f < 8; ++f) {
    const int d = h * 128 + f * 16 + lg;
    for (int r = 0; r < 4; ++r) {
      const int srow = qw0 + hg * 4 + r;
      AO[((size_t)(b * 2048 + srow)) * 2048 + d] = f2bf(acc_o[f][r] * linv[r]);
    }
  }
}

// ---------------------------------------------------------------- launch
extern "C" void kernel_launch(void* const* d_in, const int* in_sizes, int n_in,
                              void* d_out, int out_size, void* d_ws, size_t ws_size,
                              hipStream_t stream) {
  const float* x    = (const float*)d_in[0];
  const float* qkvw = (const float*)d_in[1];
  const float* ow   = (const float*)d_in[2];
  const float* cosT = (const float*)d_in[3];
  const float* sinT = (const float*)d_in[4];
  float* out = (float*)d_out;

  unsigned short* X16  = (unsigned short*)d_ws;        // 4096x2048
  unsigned short* W16  = X16  + (size_t)8388608;       // 6144x2048
  unsigned short* OW16 = W16  + (size_t)12582912;      // 2048x2048
  unsigned short* Qp   = OW16 + (size_t)4194304;       // [2][16][2048][128]
  unsigned short* Kp   = Qp   + (size_t)8388608;
  unsigned short* Vtp  = Kp   + (size_t)8388608;       // [2][16][128][2048]
  unsigned short* AO   = Vtp  + (size_t)8388608;       // 4096x2048

  cvt_all<<<24576, 256, 0, stream>>>(x, qkvw, ow, X16, W16, OW16);

  gemm_qkv_384<<<512, 512, 0, stream>>>(X16, W16, cosT, sinT, Qp, Kp, Vtp);

  attn_fwd<<<1024, 256, 0, stream>>>(Qp, Kp, Vtp, AO);

  gemm_op_256<<<256, 512, 0, stream>>>(AO, OW16, out);
}

// Round 9
// 233.048 us; speedup vs baseline: 1.0855x; 1.0855x over previous
//
#include <hip/hip_runtime.h>
#include <hip/hip_bf16.h>
#include <stdint.h>

typedef __attribute__((ext_vector_type(4))) float f32x4;
typedef __attribute__((ext_vector_type(8))) short s16x8;
typedef __attribute__((ext_vector_type(4))) short s16x4;

// XOR-swizzle of 16B-granule index within a 128B row (involution on low 3 bits)
#define SWZ(g, row) ((((g) & ~7) | (((g) ^ ((row) & 7)) & 7)))

__device__ __forceinline__ unsigned short f2bf(float f) {
  unsigned u = __builtin_bit_cast(unsigned, f);
  u += 0x7fffu + ((u >> 16) & 1u);   // round-to-nearest-even
  return (unsigned short)(u >> 16);
}

__device__ __forceinline__ void gld16(const void* g, void* l) {
  __builtin_amdgcn_global_load_lds(
      (const __attribute__((address_space(1))) void*)g,
      (__attribute__((address_space(3))) void*)l, 16, 0, 0);
}

// ---------------------------------------------------------------- fused convert
__global__ void cvt_all(const float* __restrict__ x, const float* __restrict__ qkvw,
                        const float* __restrict__ ow, unsigned short* __restrict__ X16,
                        unsigned short* __restrict__ W16, unsigned short* __restrict__ OW16) {
  int i = blockIdx.x * blockDim.x + threadIdx.x;
  const float* src; unsigned short* dst; int off;
  if (i < 2097152)      { src = x;    dst = X16;  off = i; }
  else if (i < 5242880) { src = qkvw; dst = W16;  off = i - 2097152; }
  else                  { src = ow;   dst = OW16; off = i - 5242880; }
  float4 v = ((const float4*)src)[off];
  s16x4 o;
  o[0] = (short)f2bf(v.x); o[1] = (short)f2bf(v.y);
  o[2] = (short)f2bf(v.z); o[3] = (short)f2bf(v.w);
  ((s16x4*)dst)[off] = o;
}

// ---------------------------------------------------------------- shared phase machinery
// r9: m201-complete fine phases — each phase {ds_reads, 2 G-load issues, barrier,
// lgkm0, 12 MFMA, (counted vmcnt), barrier}. vmcnt never 0 mid-loop.
#define PH_PRE \
  __builtin_amdgcn_s_barrier(); \
  asm volatile("s_waitcnt lgkmcnt(0)" ::: "memory"); \
  __builtin_amdgcn_sched_barrier(0); \
  __builtin_amdgcn_s_setprio(1);

#define PH_POST_N \
  __builtin_amdgcn_s_setprio(0); \
  __builtin_amdgcn_s_barrier();

#define PH_POST_W0 \
  __builtin_amdgcn_s_setprio(0); \
  asm volatile("s_waitcnt vmcnt(0)" ::: "memory"); \
  __builtin_amdgcn_s_barrier();

#define PH_POST_W2 \
  __builtin_amdgcn_s_setprio(0); \
  asm volatile("s_waitcnt vmcnt(2)" ::: "memory"); \
  __builtin_amdgcn_s_barrier();

#define PH_POST_W3 \
  __builtin_amdgcn_s_setprio(0); \
  asm volatile("s_waitcnt vmcnt(3)" ::: "memory"); \
  __builtin_amdgcn_s_barrier();

#define RDA(KS) \
  _Pragma("unroll") for (int j = 0; j < 4; ++j) { \
    const int ra = wm * 64 + j * 16 + lg; \
    av[j] = *(const s16x8*)(sA + ra * 128 + (SWZ(4 * (KS) + hg, ra) << 4)); }

// ---------------------------------------------------------------- QKV GEMM, 128x384 tile
#define STG_A(DST, ORG, KT) \
  _Pragma("unroll") for (int rr = 0; rr < 2; ++rr) { \
    const int G = rr * 512 + tid; const int row = G >> 3, g = G & 7; \
    gld16((const char*)((ORG) + (size_t)row * 2048 + (size_t)(KT) * 64) + (SWZ(g, row) << 4), \
          (DST) + rr * 8192 + tid * 16); }

#define STG_B2(DST, ORG, KT, R0) \
  _Pragma("unroll") for (int rr = (R0); rr < (R0) + 2; ++rr) { \
    const int G = rr * 512 + tid; const int row = G >> 3, g = G & 7; \
    gld16((const char*)((ORG) + (size_t)row * 2048 + (size_t)(KT) * 64) + (SWZ(g, row) << 4), \
          (DST) + rr * 8192 + tid * 16); }

#define RDB(KS, CH) \
  _Pragma("unroll") for (int b = 0; b < 3; ++b) { \
    const int bb = (CH) * 3 + b; \
    const int cb = (bb >> 1) * 128 + wn * 16 + (bb & 1) * 64 + lg; \
    bv[b] = *(const s16x8*)(sB + cb * 128 + (SWZ(4 * (KS) + hg, cb) << 4)); }

#define MM12(CH) \
  _Pragma("unroll") for (int j = 0; j < 4; ++j) \
    _Pragma("unroll") for (int b = 0; b < 3; ++b) \
      acc[j][(CH) * 3 + b] = __builtin_amdgcn_mfma_f32_16x16x32_bf16( \
          av[j], bv[b], acc[j][(CH) * 3 + b], 0, 0, 0);

__global__ __launch_bounds__(512, 1) void gemm_qkv_384(
    const unsigned short* __restrict__ A,
    const unsigned short* __restrict__ Bt,
    const float* __restrict__ cosT, const float* __restrict__ sinT,
    unsigned short* __restrict__ qOut, unsigned short* __restrict__ kOut,
    unsigned short* __restrict__ vtOut)
{
  __shared__ char smem[131072];   // buf b: A @ b*65536 (16KB), B @ +16384 (48KB)
  const int tid = (int)threadIdx.x;
  const int wid = tid >> 6, l = tid & 63;
  const int lg = l & 15, hg = l >> 4;
  const int wm = wid >> 2, wn = wid & 3;
  const int s = ((int)blockIdx.x & 7) * 64 + ((int)blockIdx.x >> 3);
  const int bm0 = (s & 31) * 128, bn0 = (s >> 5) * 384;

  const unsigned short* Aorg = A + (size_t)bm0 * 2048;
  const unsigned short* Borg = Bt + (size_t)bn0 * 2048;

  f32x4 acc[4][6] = {};

  // prologue: all 8 loads of tile 0 (order A0,A1,B0..B5); first 5 must land
  STG_A(smem + 0, Aorg, 0)
  STG_B2(smem + 16384, Borg, 0, 0)
  STG_B2(smem + 16384, Borg, 0, 2)
  STG_B2(smem + 16384, Borg, 0, 4)
  asm volatile("s_waitcnt vmcnt(3)" ::: "memory");
  __builtin_amdgcn_s_barrier();

  for (int t = 0; t < 31; ++t) {
    const char* sA = smem + (t & 1) * 65536;
    const char* sB = sA + 16384;
    char* dA = smem + ((t & 1) ^ 1) * 65536;
    char* dB = dA + 16384;
    s16x8 av[4], bv[3];
    RDA(0) RDB(0, 0) STG_A(dA, Aorg, t + 1)      PH_PRE MM12(0) PH_POST_W2
    RDB(0, 1)        STG_B2(dB, Borg, t + 1, 0)  PH_PRE MM12(1) PH_POST_N
    RDA(1) RDB(1, 1) STG_B2(dB, Borg, t + 1, 2)  PH_PRE MM12(1) PH_POST_N
    RDB(1, 0)        STG_B2(dB, Borg, t + 1, 4)  PH_PRE MM12(0) PH_POST_W3
  }
  {  // tail tile t = 31 (buf 1), no issues; only full drain after phase 0
    const char* sA = smem + 65536;
    const char* sB = sA + 16384;
    s16x8 av[4], bv[3];
    RDA(0) RDB(0, 0)  PH_PRE MM12(0) PH_POST_W0
    RDB(0, 1)         PH_PRE MM12(1) PH_POST_N
    RDA(1) RDB(1, 1)  PH_PRE MM12(1) PH_POST_N
    RDB(1, 0)         PH_PRE MM12(0)
    __builtin_amdgcn_s_setprio(0);
  }

  // ---- epilogue: rotary for q/k head-groups, transposed-V for v head-groups
  #pragma unroll
  for (int j = 0; j < 4; ++j) {
    const int grow0 = bm0 + wm * 64 + j * 16 + hg * 4;
    const int b_ = grow0 >> 11;
    #pragma unroll
    for (int cg = 0; cg < 3; ++cg) {
      const int og = (bn0 >> 7) + cg;
      const int tt = og >> 4, h = og & 15;
      const int d = wn * 16 + lg;
      if (tt < 2) {
        unsigned short* dst = (tt == 0) ? qOut : kOut;
        #pragma unroll
        for (int r = 0; r < 4; ++r) {
          const int gr = grow0 + r;
          const int s1 = gr & 2047;
          const float x1 = acc[j][cg * 2 + 0][r];
          const float x2 = acc[j][cg * 2 + 1][r];
          const float cv = cosT[s1 * 64 + d];
          const float sv = sinT[s1 * 64 + d];
          const size_t base = (((size_t)b_ * 16 + h) * 2048 + s1) * 128;
          dst[base + d]      = f2bf(x1 * cv - x2 * sv);
          dst[base + d + 64] = f2bf(x2 * cv + x1 * sv);
        }
      } else {
        const int s0 = grow0 & 2047;
        s16x4 p1, p2;
        #pragma unroll
        for (int r = 0; r < 4; ++r) {
          p1[r] = (short)f2bf(acc[j][cg * 2 + 0][r]);
          p2[r] = (short)f2bf(acc[j][cg * 2 + 1][r]);
        }
        *(s16x4*)(vtOut + (((size_t)b_ * 16 + h) * 128 + d)      * 2048 + s0) = p1;
        *(s16x4*)(vtOut + (((size_t)b_ * 16 + h) * 128 + d + 64) * 2048 + s0) = p2;
      }
    }
  }
}

// ---------------------------------------------------------------- out-proj GEMM, 128x256
#define RDBO(KS, CH) \
  _Pragma("unroll") for (int b = 0; b < 2; ++b) { \
    const int cb = ((CH) * 2 + b) * 64 + wn * 16 + lg; \
    bv[b] = *(const s16x8*)(sB + cb * 128 + (SWZ(4 * (KS) + hg, cb) << 4)); }

#define MMO(CH) \
  _Pragma("unroll") for (int j = 0; j < 4; ++j) \
    _Pragma("unroll") for (int b = 0; b < 2; ++b) \
      acc[j][(CH) * 2 + b] = __builtin_amdgcn_mfma_f32_16x16x32_bf16( \
          av[j], bv[b], acc[j][(CH) * 2 + b], 0, 0, 0);

__global__ __launch_bounds__(512, 1) void gemm_op_256(
    const unsigned short* __restrict__ A,
    const unsigned short* __restrict__ Bt,
    float* __restrict__ C)
{
  __shared__ char smem[98304];   // buf b @ b*49152: A 16KB, B 32KB
  const int tid = (int)threadIdx.x;
  const int wid = tid >> 6, l = tid & 63;
  const int lg = l & 15, hg = l >> 4;
  const int wm = wid >> 2, wn = wid & 3;
  const int s = ((int)blockIdx.x & 7) * 32 + ((int)blockIdx.x >> 3);
  const int bm0 = (s & 31) * 128, bn0 = (s >> 5) * 256;

  const unsigned short* Aorg = A + (size_t)bm0 * 2048;
  const unsigned short* Borg = Bt + (size_t)bn0 * 2048;

  f32x4 acc[4][4] = {};

  // prologue: all 6 loads of tile 0 (A0,A1,B0..B3); first 4 must land
  STG_A(smem + 0, Aorg, 0)
  STG_B2(smem + 16384, Borg, 0, 0)
  STG_B2(smem + 16384, Borg, 0, 2)
  asm volatile("s_waitcnt vmcnt(2)" ::: "memory");
  __builtin_amdgcn_s_barrier();

  for (int t = 0; t < 31; ++t) {
    const char* sA = smem + (t & 1) * 49152;
    const char* sB = sA + 16384;
    char* dA = smem + ((t & 1) ^ 1) * 49152;
    char* dB = dA + 16384;
    s16x8 av[4], bv[2];
    RDA(0) RDBO(0, 0) STG_A(dA, Aorg, t + 1)      PH_PRE MMO(0) PH_POST_W2
    RDBO(0, 1)        STG_B2(dB, Borg, t + 1, 0)  PH_PRE MMO(1) PH_POST_N
    RDA(1) RDBO(1, 1) STG_B2(dB, Borg, t + 1, 2)  PH_PRE MMO(1) PH_POST_N
    RDBO(1, 0)                                    PH_PRE MMO(0) PH_POST_W2
  }
  {  // tail tile t = 31 (buf 1)
    const char* sA = smem + 49152;
    const char* sB = sA + 16384;
    s16x8 av[4], bv[2];
    RDA(0) RDBO(0, 0)  PH_PRE MMO(0) PH_POST_W0
    RDBO(0, 1)         PH_PRE MMO(1) PH_POST_N
    RDA(1) RDBO(1, 1)  PH_PRE MMO(1) PH_POST_N
    RDBO(1, 0)         PH_PRE MMO(0)
    __builtin_amdgcn_s_setprio(0);
  }

  #pragma unroll
  for (int j = 0; j < 4; ++j) {
    const int row0 = bm0 + wm * 64 + j * 16 + hg * 4;
    #pragma unroll
    for (int b = 0; b < 4; ++b) {
      const int col = bn0 + b * 64 + wn * 16 + lg;
      #pragma unroll
      for (int r = 0; r < 4; ++r)
        C[(size_t)(row0 + r) * 2048 + col] = acc[j][b][r];
    }
  }
}

// ---------------------------------------------------------------- flash attention
// grid: 1024 blocks. Balanced mapping: dispatch places bids {b,b+256,b+512,b+768}
// on one CU (4 resident at 40KB LDS); give those qt = {j,31-j,8+j,23-j} so every
// CU owns exactly 66 KV-tile-units. bh = c&31 keeps 4 heads per XCD (L2-resident).
__global__ __launch_bounds__(256) void attn_fwd(
    const unsigned short* __restrict__ Qp, const unsigned short* __restrict__ Kp,
    const unsigned short* __restrict__ Vt, unsigned short* __restrict__ AO)
{
  __shared__ char sK[16384];   // [64][128] bf16, 16 granules/row, swizzled
  __shared__ char sV[16384];   // [128][64] bf16 (Vt tile), 8 granules/row, swizzled
  __shared__ char sP[8192];    // per-wave [16][64] bf16, swizzled

  const int tid = (int)threadIdx.x, w = tid >> 6, l = tid & 63;
  const int lg = l & 15, hg = l >> 4;
  const int bid = (int)blockIdx.x;
  const int p = bid >> 8, c = bid & 255;
  const int j = c >> 5, bh = c & 31;
  const int qt = (p == 0) ? j : (p == 1) ? 31 - j : (p == 2) ? 8 + j : 23 - j;
  const size_t qkBase = (size_t)bh * 2048 * 128;
  const int qw0 = qt * 64 + w * 16;
  const int qi = qw0 + lg;

  s16x8 qf[4];
  for (int ks = 0; ks < 4; ++ks)
    qf[ks] = *(const s16x8*)(Qp + qkBase + (size_t)(qw0 + lg) * 128 + ks * 32 + hg * 8);

  f32x4 acc_o[8] = {};
  float mrun = -1e30f, lrun = 0.f;
  const float SCALE = 0.08838834764831845f;   // 1/sqrt(128)
  const float L2E = 1.4426950408889634f;
  const float CS = SCALE * L2E;

  const int nkv = qt + 1;
  for (int kv = 0; kv < nkv; ++kv) {
    const int kv0 = kv * 64;
    __syncthreads();
    for (int i = 0; i < 4; ++i) {
      const int G = w * 256 + i * 64 + l;
      const int rk = G >> 4, gk = G & 15;
      gld16((const char*)(Kp + qkBase + (size_t)(kv0 + rk) * 128) + (SWZ(gk, rk) << 4),
            sK + w * 4096 + i * 1024);
      const int rv = G >> 3, gv = G & 7;
      gld16((const char*)(Vt + qkBase + (size_t)rv * 2048 + kv0) + (SWZ(gv, rv) << 4),
            sV + w * 4096 + i * 1024);
    }
    asm volatile("s_waitcnt vmcnt(0)" ::: "memory");
    __syncthreads();

    f32x4 accs[4] = {};
    for (int ks = 0; ks < 4; ++ks)
      for (int kf = 0; kf < 4; ++kf) {
        const int row = kf * 16 + lg;
        const int g = SWZ(4 * ks + hg, row);
        s16x8 kfrag = *(const s16x8*)(sK + row * 256 + (g << 4));
        accs[kf] = __builtin_amdgcn_mfma_f32_16x16x32_bf16(kfrag, qf[ks], accs[kf], 0, 0, 0);
      }

    const bool diag = (kv == qt);
    float raw[4][4];
    float mt = -1e30f;
    #pragma unroll
    for (int kf = 0; kf < 4; ++kf)
      #pragma unroll
      for (int r = 0; r < 4; ++r) {
        float s = accs[kf][r];
        if (diag) {
          const int jj = kv0 + kf * 16 + hg * 4 + r;
          s = (jj > qi) ? -1e30f : s;
        }
        raw[kf][r] = s;
        mt = fmaxf(mt, s);
      }
    mt = fmaxf(mt, __shfl_xor(mt, 16));
    mt = fmaxf(mt, __shfl_xor(mt, 32));
    mt *= SCALE;
    if (!__all(mt - mrun <= 8.0f)) {
      const float mnew = fmaxf(mrun, mt);
      const float alpha = exp2f((mrun - mnew) * L2E);
      float ar[4];
      #pragma unroll
      for (int r = 0; r < 4; ++r) ar[r] = __shfl(alpha, hg * 4 + r);
      #pragma unroll
      for (int f = 0; f < 8; ++f)
        #pragma unroll
        for (int r = 0; r < 4; ++r) acc_o[f][r] *= ar[r];
      lrun *= alpha;
      mrun = mnew;
    }
    const float mL = mrun * L2E;
    float ls = 0.f;
    char* pw = sP + w * 2048;
    #pragma unroll
    for (int kf = 0; kf < 4; ++kf) {
      s16x4 pk;
      #pragma unroll
      for (int r = 0; r < 4; ++r) {
        const float e = exp2f(raw[kf][r] * CS - mL);
        ls += e;
        pk[r] = (short)f2bf(e);
      }
      const int j0 = kf * 16 + hg * 4;
      *(s16x4*)(pw + lg * 128 + (SWZ(j0 >> 3, lg) << 4) + ((j0 * 2) & 15)) = pk;
    }
    ls += __shfl_xor(ls, 16);
    ls += __shfl_xor(ls, 32);
    lrun += ls;
    asm volatile("" ::: "memory");

    for (int jc = 0; jc < 2; ++jc) {
      const int gp = SWZ(hg + 4 * jc, lg);
      s16x8 pa = *(const s16x8*)(pw + lg * 128 + (gp << 4));
      for (int f = 0; f < 8; ++f) {
        const int rv = f * 16 + lg;
        const int gv = SWZ(hg + 4 * jc, rv);
        s16x8 vb = *(const s16x8*)(sV + rv * 128 + (gv << 4));
        acc_o[f] = __builtin_amdgcn_mfma_f32_16x16x32_bf16(pa, vb, acc_o[f], 0, 0, 0);
      }
    }
  }

  float linv[4];
  for (int r = 0; r < 4; ++r) linv[r] = 1.0f / __shfl(lrun, hg * 4 + r);
  const int b = bh >> 4, h = bh & 15;
  for (int f = 0; f < 8; ++f) {
    const int d = h * 128 + f * 16 + lg;
    for (int r = 0; r < 4; ++r) {
      const int srow = qw0 + hg * 4 + r;
      AO[((size_t)(b * 2048 + srow)) * 2048 + d] = f2bf(acc_o[f][r] * linv[r]);
    }
  }
}

// ---------------------------------------------------------------- launch
extern "C" void kernel_launch(void* const* d_in, const int* in_sizes, int n_in,
                              void* d_out, int out_size, void* d_ws, size_t ws_size,
                              hipStream_t stream) {
  const float* x    = (const float*)d_in[0];
  const float* qkvw = (const float*)d_in[1];
  const float* ow   = (const float*)d_in[2];
  const float* cosT = (const float*)d_in[3];
  const float* sinT = (const float*)d_in[4];
  float* out = (float*)d_out;

  unsigned short* X16  = (unsigned short*)d_ws;        // 4096x2048
  unsigned short* W16  = X16  + (size_t)8388608;       // 6144x2048
  unsigned short* OW16 = W16  + (size_t)12582912;      // 2048x2048
  unsigned short* Qp   = OW16 + (size_t)4194304;       // [2][16][2048][128]
  unsigned short* Kp   = Qp   + (size_t)8388608;
  unsigned short* Vtp  = Kp   + (size_t)8388608;       // [2][16][128][2048]
  unsigned short* AO   = Vtp  + (size_t)8388608;       // 4096x2048

  cvt_all<<<24576, 256, 0, stream>>>(x, qkvw, ow, X16, W16, OW16);

  gemm_qkv_384<<<512, 512, 0, stream>>>(X16, W16, cosT, sinT, Qp, Kp, Vtp);

  attn_fwd<<<1024, 256, 0, stream>>>(Qp, Kp, Vtp, AO);

  gemm_op_256<<<256, 512, 0, stream>>>(AO, OW16, out);
}